// Round 3
// baseline (5853.008 us; speedup 1.0000x reference)
//
#include <hip/hip_runtime.h>
#include <hip/hip_cooperative_groups.h>
#include <hip/hip_bf16.h>
#include <stdint.h>

namespace cg = cooperative_groups;

// Problem constants
#define BATCH_ 256
#define SEQ_   128
#define DIN_   768
#define HID_   512
#define NG_    2048   // 4*HID
#define NCLS_  9

typedef unsigned short u16;
typedef __attribute__((ext_vector_type(8))) short bf16x8;
typedef __attribute__((ext_vector_type(4))) float f32x4;

__device__ __forceinline__ float bf2f(u16 u) {
  return __builtin_bit_cast(float, (uint32_t)u << 16);
}
__device__ __forceinline__ u16 f2bf(float f) {
  uint32_t x = __builtin_bit_cast(uint32_t, f);
  uint32_t r = (x + 0x7fffu + ((x >> 16) & 1u)) >> 16;  // RNE
  return (u16)r;
}

// async global->LDS, 16B per lane. LDS dest must be linear in lane order.
__device__ __forceinline__ void gload_lds16(const void* g, void* l) {
#if defined(__has_builtin)
#if __has_builtin(__builtin_amdgcn_global_load_lds)
  __builtin_amdgcn_global_load_lds((const __attribute__((address_space(1))) void*)g,
                                   (__attribute__((address_space(3))) void*)l, 16, 0, 0);
  return;
#endif
#endif
  *(uint4*)l = *(const uint4*)g;  // fallback (sync copy through regs)
}

// ---------------- f32 -> bf16 cast (weights) ----------------
__global__ void castk(const float* __restrict__ s, u16* __restrict__ d, int n4) {
  int i = blockIdx.x * blockDim.x + threadIdx.x;
  if (i < n4) {
    float4 v = ((const float4*)s)[i];
    ushort4 o;
    o.x = f2bf(v.x); o.y = f2bf(v.y); o.z = f2bf(v.z); o.w = f2bf(v.w);
    ((ushort4*)d)[i] = o;
  }
}

// cast into packed [W2|R2] rows: src (2048,512) f32 -> dst rows stride 1024, col offset dstOff
__global__ void cast2(const float* __restrict__ s, u16* __restrict__ d, int dstOff) {
  int i = blockIdx.x * blockDim.x + threadIdx.x;  // f32x4 chunks, 2048*128 total
  if (i < 2048 * 128) {
    int row = i >> 7, c4 = i & 127;
    float4 v = ((const float4*)s)[i];
    ushort4 o;
    o.x = f2bf(v.x); o.y = f2bf(v.y); o.z = f2bf(v.z); o.w = f2bf(v.w);
    ((ushort4*)(d + (size_t)row * 1024 + dstOff))[c4] = o;
  }
}

// ---------------- embed gather + add pos + cast, (S,B,768) bf16 ----------------
__global__ __launch_bounds__(192) void embed_k(const int* __restrict__ ids,
                                               const float* __restrict__ tok,
                                               const float* __restrict__ pos,
                                               u16* __restrict__ X) {
  const int row = blockIdx.x;          // row = t*256 + b
  const int t = row >> 8, b = row & 255;
  const int id = ids[b * SEQ_ + t];    // input_ids is (B,S)
  const float4* tr = (const float4*)(tok + (size_t)id * DIN_);
  const float4* pr = (const float4*)(pos + (size_t)t * DIN_);
  const int i = threadIdx.x;           // 192 threads * 4 floats = 768
  float4 v = tr[i], p = pr[i];
  ushort4 o;
  o.x = f2bf(v.x + p.x); o.y = f2bf(v.y + p.y);
  o.z = f2bf(v.z + p.z); o.w = f2bf(v.w + p.w);
  ((ushort4*)(X + (size_t)row * DIN_))[i] = o;
}

// ---------------- bf16 GEMM, C[m][n] = sum_k A[m][k]*B[n][k] + bias[n] ----------------
// 128x128 tile, BK=64, 4 waves (2x2 of 64x64), 16x16x32 MFMA (m97 structure).
__global__ __launch_bounds__(256) void gemm_bt(const u16* __restrict__ A,
                                               const u16* __restrict__ Bm,
                                               const float* __restrict__ bias,
                                               u16* __restrict__ C,
                                               int M, int N, int K) {
  __shared__ __align__(16) u16 As[128 * 64];
  __shared__ __align__(16) u16 Bs[128 * 64];
  const int tid = threadIdx.x;
  const int lane = tid & 63;
  const int wave = tid >> 6;
  const int m0 = blockIdx.y * 128;
  const int n0 = blockIdx.x * 128;
  const int wm = (wave >> 1) * 64;
  const int wn = (wave & 1) * 64;
  const int lr = lane & 15;
  const int lg = lane >> 4;
  f32x4 acc[4][4] = {};

  for (int k0 = 0; k0 < K; k0 += 64) {
#pragma unroll
    for (int it = 0; it < 4; ++it) {
      int e = it * 256 + tid;
      int r = e >> 3, c8 = (e & 7) * 8;
      gload_lds16(A + (size_t)(m0 + r) * K + k0 + c8, &As[e * 8]);
      gload_lds16(Bm + (size_t)(n0 + r) * K + k0 + c8, &Bs[e * 8]);
    }
    __syncthreads();
#pragma unroll
    for (int kk = 0; kk < 64; kk += 32) {
      bf16x8 af[4], bfr[4];
#pragma unroll
      for (int i = 0; i < 4; ++i) {
        af[i]  = *(const bf16x8*)&As[(wm + i * 16 + lr) * 64 + kk + lg * 8];
        bfr[i] = *(const bf16x8*)&Bs[(wn + i * 16 + lr) * 64 + kk + lg * 8];
      }
#pragma unroll
      for (int i = 0; i < 4; ++i)
#pragma unroll
        for (int j = 0; j < 4; ++j)
          acc[i][j] = __builtin_amdgcn_mfma_f32_16x16x32_bf16(af[i], bfr[j], acc[i][j], 0, 0, 0);
    }
    __syncthreads();
  }
  // epilogue: C/D layout col=lane&15, row=(lane>>4)*4+q  [m89-verified]
#pragma unroll
  for (int i = 0; i < 4; ++i) {
#pragma unroll
    for (int j = 0; j < 4; ++j) {
      int col = n0 + wn + j * 16 + lr;
      float bv = bias[col];
#pragma unroll
      for (int q = 0; q < 4; ++q) {
        int row = m0 + wm + i * 16 + lg * 4 + q;
        C[(size_t)row * N + col] = f2bf(acc[i][j][q] + bv);
      }
    }
  }
}

// ---------------- persistent wavefront recurrence kernel ----------------
// 256 blocks (cooperative): blocks [0,128) = layer1, [128,256) = layer2.
// Step k (0..SEQ): L1 computes t=k (k<SEQ), L2 computes t=k-1 (k>=1); grid.sync().
// SLOT(t) = Acat + (t+1)*BATCH*1024, row b = [ h1(t) | h2(t-1) ].
//   Both layers at step k read SLOT(k-1) and write SLOT(k). L1 K=512, L2 K=1024.
// Tile: 64 batch rows x 16 hid cols x 4 gates per block. 8 waves = (mq 0..3, nh 0..1);
//   wave does 1 A-frag (16 rows) x 2 B-frags (gates 2nh,2nh+1) per kk -> 2 MFMA.
// A (=h) staged in LDS (XOR-swizzled via pre-swizzled global source);
// B (=weights) streamed from global direct-to-reg (XCD-L2 resident: block is CU-pinned).
// Cell state kept in LDS across all steps.
__global__ __launch_bounds__(512, 1) void lstm_persist(
    u16* __restrict__ Acat,
    const u16* __restrict__ Xpre,    // (S,256,2048) bf16
    const u16* __restrict__ R1b,     // (2048,512)
    const u16* __restrict__ W2cat,   // (2048,1024) = [W2|R2]
    const float* __restrict__ b2) {
  __shared__ __align__(16) u16 As[64 * 512];   // 64KB
  __shared__ float Gs[4][64][18];              // 18.4KB (pad 18: conflict-light)
  __shared__ float Cs[64][16];                 // 4KB cell state
  cg::grid_group grid = cg::this_grid();

  const int tid = threadIdx.x;
  const int lane = tid & 63;
  const int w = tid >> 6;            // 0..7
  int bid = blockIdx.x;
  const bool isL2 = bid >= 128;
  if (isL2) bid -= 128;
  const int m0 = (bid & 3) * 64;     // batch tile
  const int j0 = (bid >> 2) * 16;    // hid-col tile
  const int mq = w >> 1;             // m-frag group (16 rows each)
  const int nh = w & 1;              // gate pair (2nh, 2nh+1)
  const int lr = lane & 15, lg = lane >> 4;
  const int npass = isL2 ? 2 : 1;
  const size_t bstride = isL2 ? 1024 : 512;
  const u16* Bmat = isL2 ? W2cat : R1b;
  const u16* Brow0 = Bmat + (size_t)((2 * nh + 0) * 512 + j0 + lr) * bstride + lg * 8;
  const u16* Brow1 = Bmat + (size_t)((2 * nh + 1) * 512 + j0 + lr) * bstride + lg * 8;

  // zero cell state (each thread owns its 2 cells for the whole kernel)
#pragma unroll
  for (int u = 0; u < 2; ++u) {
    int cell = u * 512 + tid;
    Cs[cell >> 4][cell & 15] = 0.f;
  }

  for (int k = 0; k <= SEQ_; ++k) {
    const bool active = isL2 ? (k >= 1) : (k < SEQ_);
    if (active) {
      const u16* Aprev = Acat + (size_t)k * (BATCH_ * 1024);        // SLOT(k-1)
      u16* Aout = Acat + (size_t)(k + 1) * (BATCH_ * 1024);         // SLOT(k)
      f32x4 acc0 = {}, acc1 = {};
      for (int pass = 0; pass < npass; ++pass) {
        const int kbase = pass * 512;
        // stage A: 64 rows x 512 cols, LDS[r][c] = G[r][c ^ (r&7)] (c = 16B chunk)
#pragma unroll
        for (int it = 0; it < 8; ++it) {
          int e = it * 512 + tid;
          int r = e >> 6;
          int csrc = (e & 63) ^ (r & 7);
          gload_lds16(Aprev + (size_t)(m0 + r) * 1024 + kbase + csrc * 8, &As[e * 8]);
        }
        __syncthreads();
#pragma unroll
        for (int kk = 0; kk < 512; kk += 32) {
          bf16x8 bf0 = *(const bf16x8*)(Brow0 + kbase + kk);
          bf16x8 bf1 = *(const bf16x8*)(Brow1 + kbase + kk);
          int cA = (kk >> 3) + lg;          // global 16B chunk index
          int cx = (cA ^ (lr & 7)) * 8;     // swizzled elem offset
          bf16x8 a = *(const bf16x8*)&As[(mq * 16 + lr) * 512 + cx];
          acc0 = __builtin_amdgcn_mfma_f32_16x16x32_bf16(a, bf0, acc0, 0, 0, 0);
          acc1 = __builtin_amdgcn_mfma_f32_16x16x32_bf16(a, bf1, acc1, 0, 0, 0);
        }
        if (pass + 1 < npass) __syncthreads();
      }
      // epilogue: add Xpre (L1) / b2 (L2); publish gates to LDS.
      // C/D layout: col(n)=lane&15, row(m)=(lane>>4)*4+q
      const u16* XpreK = Xpre + (size_t)k * (BATCH_ * NG_);
#pragma unroll
      for (int q = 0; q < 4; ++q) {
        int rl = mq * 16 + lg * 4 + q;
        float add0, add1;
        if (isL2) {
          add0 = b2[(2 * nh + 0) * 512 + j0 + lr];
          add1 = b2[(2 * nh + 1) * 512 + j0 + lr];
        } else {
          add0 = bf2f(XpreK[(size_t)(m0 + rl) * NG_ + (2 * nh + 0) * 512 + j0 + lr]);
          add1 = bf2f(XpreK[(size_t)(m0 + rl) * NG_ + (2 * nh + 1) * 512 + j0 + lr]);
        }
        Gs[2 * nh + 0][rl][lr] = acc0[q] + add0;
        Gs[2 * nh + 1][rl][lr] = acc1[q] + add1;
      }
      __syncthreads();
      // cell update: 64x16 = 1024 cells / 512 threads (fixed thread->cell ownership)
      const int off = isL2 ? 512 : 0;
#pragma unroll
      for (int u = 0; u < 2; ++u) {
        int cell = u * 512 + tid;
        int bl = cell >> 4, jl = cell & 15;
        float gi = Gs[0][bl][jl], gf = Gs[1][bl][jl], gm = Gs[2][bl][jl], go = Gs[3][bl][jl];
        float iv = 1.f / (1.f + expf(-gi));
        float fv = 1.f / (1.f + expf(-gf));
        float mv = tanhf(gm);
        float ov = 1.f / (1.f + expf(-go));
        float cn = mv * iv + fv * Cs[bl][jl];
        Cs[bl][jl] = cn;
        Aout[(size_t)(m0 + bl) * 1024 + off + j0 + jl] = f2bf(ov * tanhf(cn));
      }
      __syncthreads();
    }
    grid.sync();
  }
}

// ---------------- output projection from Acat: h2(t) = SLOT(t+1)[:,512:] ----------------
__global__ __launch_bounds__(320) void out_proj(const u16* __restrict__ Acat,
                                                const float* __restrict__ Wo,
                                                const float* __restrict__ bo,
                                                float* __restrict__ out) {
  __shared__ __align__(16) u16 Hs[32 * 520];  // +8 pad kills bank conflicts
  const int r0 = blockIdx.x * 32;             // flat row = t*256 + b
  const int tid = threadIdx.x;
  for (int e = tid; e < 2048; e += 320) {
    int rl = e >> 6, k8 = (e & 63) * 8;
    int r = r0 + rl, t = r >> 8, b = r & 255;
    *(uint4*)&Hs[rl * 520 + k8] =
        *(const uint4*)(Acat + (size_t)(t + 2) * (BATCH_ * 1024) + (size_t)b * 1024 + 512 + k8);
  }
  __syncthreads();
  if (tid < 288) {
    int rl = tid / 9, cls = tid - rl * 9;
    const u16* h = &Hs[rl * 520];
    const float* wv = Wo + cls * HID_;
    float s = bo[cls];
#pragma unroll 8
    for (int k = 0; k < HID_; ++k) s += bf2f(h[k]) * wv[k];
    int r = r0 + rl, t = r >> 8, b = r & 255;
    out[((size_t)b * SEQ_ + t) * NCLS_ + cls] = s;
  }
}

extern "C" void kernel_launch(void* const* d_in, const int* in_sizes, int n_in,
                              void* d_out, int out_size, void* d_ws, size_t ws_size,
                              hipStream_t stream) {
  (void)in_sizes; (void)n_in; (void)out_size; (void)ws_size;
  const int*   ids = (const int*)d_in[0];
  const float* tok = (const float*)d_in[1];
  const float* pos = (const float*)d_in[2];
  const float* W1  = (const float*)d_in[3];
  const float* R1  = (const float*)d_in[4];
  const float* b1  = (const float*)d_in[5];
  const float* W2  = (const float*)d_in[6];
  const float* R2  = (const float*)d_in[7];
  const float* b2  = (const float*)d_in[8];
  const float* Wo  = (const float*)d_in[9];
  const float* bo  = (const float*)d_in[10];
  float* out = (float*)d_out;

  // workspace layout (~212 MB); Acat overlays Xbf (dead after phase A)
  char* p = (char*)d_ws;
  auto alloc = [&](size_t bytes) { char* q = p; p += (bytes + 255) & ~(size_t)255; return q; };
  u16*  W1b  = (u16*)alloc((size_t)NG_ * DIN_ * 2);
  u16*  R1b  = (u16*)alloc((size_t)NG_ * HID_ * 2);
  u16*  W2c  = (u16*)alloc((size_t)NG_ * 1024 * 2);               // [W2|R2]
  size_t xbf_bytes  = (size_t)SEQ_ * BATCH_ * DIN_ * 2;           // 50.3 MB
  size_t acat_bytes = (size_t)(SEQ_ + 2) * BATCH_ * 1024 * 2;     // 68.2 MB
  u16*  Xbf  = (u16*)alloc(acat_bytes > xbf_bytes ? acat_bytes : xbf_bytes);
  u16*  Acat = Xbf;                                               // overlay
  u16*  Xpre = (u16*)alloc((size_t)SEQ_ * BATCH_ * NG_ * 2);      // 134 MB

  // weight casts
  castk<<<dim3((NG_ * DIN_ / 4 + 255) / 256), 256, 0, stream>>>(W1, W1b, NG_ * DIN_ / 4);
  castk<<<dim3((NG_ * HID_ / 4 + 255) / 256), 256, 0, stream>>>(R1, R1b, NG_ * HID_ / 4);
  cast2<<<dim3(1024), 256, 0, stream>>>(W2, W2c, 0);
  cast2<<<dim3(1024), 256, 0, stream>>>(R2, W2c, 512);

  // embeds -> (S,B,768) bf16
  embed_k<<<dim3(SEQ_ * BATCH_), 192, 0, stream>>>(ids, tok, pos, Xbf);

  // phase A: X1pre = X @ W1^T + b1   (32768 x 2048, K=768)
  gemm_bt<<<dim3(NG_ / 128, SEQ_ * BATCH_ / 128), 256, 0, stream>>>(
      Xbf, W1b, b1, Xpre, SEQ_ * BATCH_, NG_, DIN_);

  // Xbf now dead; zero SLOT(-1) and SLOT(0) (h1(-1)=0, h2(-1)=0)
  hipMemsetAsync(Acat, 0, (size_t)2 * BATCH_ * 1024 * 2, stream);

  // persistent cooperative recurrence (129 grid-sync'd wavefront steps)
  {
    u16* Acat_a = Acat;
    const u16* Xpre_a = Xpre;
    const u16* R1b_a = R1b;
    const u16* W2c_a = W2c;
    const float* b2_a = b2;
    void* args[] = {(void*)&Acat_a, (void*)&Xpre_a, (void*)&R1b_a,
                    (void*)&W2c_a, (void*)&b2_a};
    hipLaunchCooperativeKernel((const void*)lstm_persist, dim3(256), dim3(512),
                               args, 0, stream);
  }

  // logits
  out_proj<<<dim3(SEQ_ * BATCH_ / 32), 320, 0, stream>>>(Acat, Wo, bo, out);
}

// Round 4
// 1506.253 us; speedup vs baseline: 3.8858x; 3.8858x over previous
//
#include <hip/hip_runtime.h>
#include <hip/hip_bf16.h>
#include <stdint.h>

// Problem constants
#define BATCH_ 256
#define SEQ_   128
#define DIN_   768
#define HID_   512
#define NG_    2048   // 4*HID
#define NCLS_  9

typedef unsigned short u16;
typedef unsigned long long u64;
typedef __attribute__((ext_vector_type(8))) short bf16x8;
typedef __attribute__((ext_vector_type(4))) float f32x4;

__device__ __forceinline__ float bf2f(u16 u) {
  return __builtin_bit_cast(float, (uint32_t)u << 16);
}
__device__ __forceinline__ u16 f2bf(float f) {
  uint32_t x = __builtin_bit_cast(uint32_t, f);
  uint32_t r = (x + 0x7fffu + ((x >> 16) & 1u)) >> 16;  // RNE
  return (u16)r;
}

// async global->LDS, 16B per lane. LDS dest must be linear in lane order.
__device__ __forceinline__ void gload_lds16(const void* g, void* l) {
#if defined(__has_builtin)
#if __has_builtin(__builtin_amdgcn_global_load_lds)
  __builtin_amdgcn_global_load_lds((const __attribute__((address_space(1))) void*)g,
                                   (__attribute__((address_space(3))) void*)l, 16, 0, 0);
  return;
#endif
#endif
  *(uint4*)l = *(const uint4*)g;  // fallback (sync copy through regs)
}

// ---------------- f32 -> bf16 cast (weights) ----------------
__global__ void castk(const float* __restrict__ s, u16* __restrict__ d, int n4) {
  int i = blockIdx.x * blockDim.x + threadIdx.x;
  if (i < n4) {
    float4 v = ((const float4*)s)[i];
    ushort4 o;
    o.x = f2bf(v.x); o.y = f2bf(v.y); o.z = f2bf(v.z); o.w = f2bf(v.w);
    ((ushort4*)d)[i] = o;
  }
}

// cast into packed [W2|R2] rows: src (2048,512) f32 -> dst rows stride 1024, col offset dstOff
__global__ void cast2(const float* __restrict__ s, u16* __restrict__ d, int dstOff) {
  int i = blockIdx.x * blockDim.x + threadIdx.x;  // f32x4 chunks, 2048*128 total
  if (i < 2048 * 128) {
    int row = i >> 7, c4 = i & 127;
    float4 v = ((const float4*)s)[i];
    ushort4 o;
    o.x = f2bf(v.x); o.y = f2bf(v.y); o.z = f2bf(v.z); o.w = f2bf(v.w);
    ((ushort4*)(d + (size_t)row * 1024 + dstOff))[c4] = o;
  }
}

// ---------------- embed gather + add pos + cast, (S,B,768) bf16 ----------------
__global__ __launch_bounds__(192) void embed_k(const int* __restrict__ ids,
                                               const float* __restrict__ tok,
                                               const float* __restrict__ pos,
                                               u16* __restrict__ X) {
  const int row = blockIdx.x;          // row = t*256 + b
  const int t = row >> 8, b = row & 255;
  const int id = ids[b * SEQ_ + t];    // input_ids is (B,S)
  const float4* tr = (const float4*)(tok + (size_t)id * DIN_);
  const float4* pr = (const float4*)(pos + (size_t)t * DIN_);
  const int i = threadIdx.x;           // 192 threads * 4 floats = 768
  float4 v = tr[i], p = pr[i];
  ushort4 o;
  o.x = f2bf(v.x + p.x); o.y = f2bf(v.y + p.y);
  o.z = f2bf(v.z + p.z); o.w = f2bf(v.w + p.w);
  ((ushort4*)(X + (size_t)row * DIN_))[i] = o;
}

// ---------------- bf16 GEMM, C[m][n] = sum_k A[m][k]*B[n][k] + bias[n] ----------------
__global__ __launch_bounds__(256) void gemm_bt(const u16* __restrict__ A,
                                               const u16* __restrict__ Bm,
                                               const float* __restrict__ bias,
                                               u16* __restrict__ C,
                                               int M, int N, int K) {
  __shared__ __align__(16) u16 As[128 * 64];
  __shared__ __align__(16) u16 Bs[128 * 64];
  const int tid = threadIdx.x;
  const int lane = tid & 63;
  const int wave = tid >> 6;
  const int m0 = blockIdx.y * 128;
  const int n0 = blockIdx.x * 128;
  const int wm = (wave >> 1) * 64;
  const int wn = (wave & 1) * 64;
  const int lr = lane & 15;
  const int lg = lane >> 4;
  f32x4 acc[4][4] = {};

  for (int k0 = 0; k0 < K; k0 += 64) {
#pragma unroll
    for (int it = 0; it < 4; ++it) {
      int e = it * 256 + tid;
      int r = e >> 3, c8 = (e & 7) * 8;
      gload_lds16(A + (size_t)(m0 + r) * K + k0 + c8, &As[e * 8]);
      gload_lds16(Bm + (size_t)(n0 + r) * K + k0 + c8, &Bs[e * 8]);
    }
    __syncthreads();
#pragma unroll
    for (int kk = 0; kk < 64; kk += 32) {
      bf16x8 af[4], bfr[4];
#pragma unroll
      for (int i = 0; i < 4; ++i) {
        af[i]  = *(const bf16x8*)&As[(wm + i * 16 + lr) * 64 + kk + lg * 8];
        bfr[i] = *(const bf16x8*)&Bs[(wn + i * 16 + lr) * 64 + kk + lg * 8];
      }
#pragma unroll
      for (int i = 0; i < 4; ++i)
#pragma unroll
        for (int j = 0; j < 4; ++j)
          acc[i][j] = __builtin_amdgcn_mfma_f32_16x16x32_bf16(af[i], bfr[j], acc[i][j], 0, 0, 0);
    }
    __syncthreads();
  }
#pragma unroll
  for (int i = 0; i < 4; ++i) {
#pragma unroll
    for (int j = 0; j < 4; ++j) {
      int col = n0 + wn + j * 16 + lr;
      float bv = bias[col];
#pragma unroll
      for (int q = 0; q < 4; ++q) {
        int row = m0 + wm + i * 16 + lg * 4 + q;
        C[(size_t)row * N + col] = f2bf(acc[i][j][q] + bv);
      }
    }
  }
}

// ---------------- persistent per-layer chain kernel ----------------
// 256 blocks, cooperative (co-residency for spin-wait). block = (m = bid&7 -> 32
// batch rows, j = bid>>3 -> 16 hidden cols, all 4 gates).
// 8 waves = (mh, nh, kh): mh = 16-row half, nh = gate pair, kh = K half.
// Recurrent weights held in VGPRs for the whole kernel (L1: 64, L2: 128 VGPR/wave).
// h chain sync: per-(t,m) flags, relaxed agent atomics; h data via agent-scope
// atomic stores (write-through) + atomic loads (L2-bypass). No fences -> weights
// and Xpre stay cache-resident. L2 layer reads h1 (previous kernel's output)
// via normal global_load_lds (kernel-boundary coherent).
template <int L2L>
__global__ __launch_bounds__(512, 2) void lstm_chain(
    const u16* __restrict__ Hother,   // L2: H1all (S,256,512). L1: unused
    u16* __restrict__ Hself,          // chain output (S,256,512)
    const u16* __restrict__ Xpre,     // L1: (S,256,2048) x@W+b. L2: unused
    const float* __restrict__ b2,     // L2 bias
    const u16* __restrict__ Bw,       // L1: R1b (2048,512). L2: W2c (2048,1024)=[W2|R2]
    int* __restrict__ flags) {        // (S,8)
  constexpr int KKL = L2L ? 16 : 8;       // kk steps per K-half
  constexpr int BSTRIDE = L2L ? 1024 : 512;
  __shared__ __align__(16) u16 As1[32 * 512];             // 32KB (L2: h1 half)
  __shared__ __align__(16) u16 As2[L2L ? 32 * 512 : 64];  // L2 only: h2 half
  __shared__ float Gs[2][4][32][17];                      // kh-partial gate sums
  __shared__ float Cs[32][16];                            // cell state

  const int tid = threadIdx.x;
  const int lane = tid & 63;
  const int w = tid >> 6;
  const int mh = w & 1, nh = (w >> 1) & 1, kh = w >> 2;
  const int m = blockIdx.x & 7;
  const int m0 = m * 32;
  const int j0 = (blockIdx.x >> 3) * 16;
  const int lr = lane & 15, lg = lane >> 4;

  // persistent recurrent-weight fragments (static indices only)
  bf16x8 Breg[2][KKL];
#pragma unroll
  for (int i = 0; i < 2; ++i) {
#pragma unroll
    for (int kkl = 0; kkl < KKL; ++kkl) {
      int row = (2 * nh + i) * 512 + j0 + lr;
      int col = kh * (KKL * 32) + kkl * 32 + lg * 8;
      Breg[i][kkl] = *(const bf16x8*)&Bw[(size_t)row * BSTRIDE + col];
    }
  }
  if (tid < 256) {
    int bl = tid >> 3, jl = (tid & 7) * 2;
    Cs[bl][jl] = 0.f; Cs[bl][jl + 1] = 0.f;
  }
  __syncthreads();

  for (int t = 0; t < SEQ_; ++t) {
    // L2: issue h1(t) gload early (independent of flag)
    if (L2L) {
      const u16* src = Hother + (size_t)t * (BATCH_ * HID_);
#pragma unroll
      for (int it = 0; it < 4; ++it) {
        int e = it * 512 + tid;
        int r = e >> 6, c16 = e & 63;
        int cs = c16 ^ (r & 7);                       // pre-swizzled source
        gload_lds16(src + (size_t)(m0 + r) * HID_ + cs * 8, &As1[e * 8]);
      }
    }
    // wait for sibling blocks' h(t-1)
    if (t > 0 && tid == 0) {
      int spins = 0;
      while (__hip_atomic_load(&flags[(t - 1) * 8 + m], __ATOMIC_RELAXED,
                               __HIP_MEMORY_SCOPE_AGENT) < 32) {
        __builtin_amdgcn_s_sleep(1);
        if (++spins > (1 << 22)) break;   // bounded: wrong > hung
      }
    }
    __syncthreads();
    // stage h(t-1) via coherent loads + swizzled ds_write
    if (t > 0) {
      const u64* s64 = (const u64*)(Hself + (size_t)(t - 1) * (BATCH_ * HID_));
      u16* dstA = (L2L ? As2 : As1);
#pragma unroll
      for (int i = 0; i < 8; ++i) {
        int e = i * 512 + tid;
        int r = e >> 7, c8 = e & 127;
        u64 v = __hip_atomic_load(&s64[(size_t)(m0 + r) * 128 + c8],
                                  __ATOMIC_RELAXED, __HIP_MEMORY_SCOPE_AGENT);
        int c16 = c8 >> 1, lo = c8 & 1;
        *(u64*)((char*)dstA + r * 1024 + (((c16 ^ (r & 7)) << 4) | (lo << 3))) = v;
      }
    }
    __syncthreads();
    // MFMA: this wave's K half
    f32x4 acc0 = {}, acc1 = {};
    const bool act = L2L ? (kh == 0 || t > 0) : (t > 0);
    if (act) {
      const u16* AsX = (L2L && kh) ? As2 : As1;
#pragma unroll
      for (int kkl = 0; kkl < KKL; ++kkl) {
        int c = (L2L ? 0 : kh * 32) + kkl * 4 + lg;
        bf16x8 a = *(const bf16x8*)((const char*)AsX + (mh * 16 + lr) * 1024 +
                                    ((c ^ (lr & 7)) << 4));
        acc0 = __builtin_amdgcn_mfma_f32_16x16x32_bf16(a, Breg[0][kkl], acc0, 0, 0, 0);
        acc1 = __builtin_amdgcn_mfma_f32_16x16x32_bf16(a, Breg[1][kkl], acc1, 0, 0, 0);
      }
    }
    // publish kh-partial gate pre-activations (C/D: col=lane&15, row=(lane>>4)*4+q)
#pragma unroll
    for (int q = 0; q < 4; ++q) {
      Gs[kh][2 * nh + 0][mh * 16 + lg * 4 + q][lr] = acc0[q];
      Gs[kh][2 * nh + 1][mh * 16 + lg * 4 + q][lr] = acc1[q];
    }
    __syncthreads();
    // cell update: 512 cells, threads 0..255 x 2 adjacent cells
    if (tid < 256) {
      int bl = tid >> 3, jl = (tid & 7) * 2;
      float G[4][2];
#pragma unroll
      for (int g = 0; g < 4; ++g) {
        float a0 = Gs[0][g][bl][jl] + Gs[1][g][bl][jl];
        float a1 = Gs[0][g][bl][jl + 1] + Gs[1][g][bl][jl + 1];
        if (L2L) {
          a0 += b2[g * 512 + j0 + jl];
          a1 += b2[g * 512 + j0 + jl + 1];
        } else {
          uint32_t xp = *(const uint32_t*)&Xpre[(size_t)t * (BATCH_ * NG_) +
                                                (size_t)(m0 + bl) * NG_ + g * 512 + j0 + jl];
          a0 += bf2f((u16)xp);
          a1 += bf2f((u16)(xp >> 16));
        }
        G[g][0] = a0; G[g][1] = a1;
      }
      uint32_t pack = 0;
#pragma unroll
      for (int u = 0; u < 2; ++u) {
        float iv = 1.f / (1.f + expf(-G[0][u]));
        float fv = 1.f / (1.f + expf(-G[1][u]));
        float mv = tanhf(G[2][u]);
        float ov = 1.f / (1.f + expf(-G[3][u]));
        float cn = mv * iv + fv * Cs[bl][jl + u];
        Cs[bl][jl + u] = cn;
        pack |= (uint32_t)f2bf(ov * tanhf(cn)) << (16 * u);
      }
      __hip_atomic_store((uint32_t*)(Hself + (size_t)t * (BATCH_ * HID_) +
                                     (size_t)(m0 + bl) * HID_ + j0 + jl),
                         pack, __ATOMIC_RELAXED, __HIP_MEMORY_SCOPE_AGENT);
    }
    __syncthreads();  // per-wave vmcnt(0) drain before barrier -> stores visible
    if (tid == 0)
      __hip_atomic_fetch_add(&flags[t * 8 + m], 1, __ATOMIC_RELAXED,
                             __HIP_MEMORY_SCOPE_AGENT);
  }
}

// ---------------- output projection: out[b][t][cls] = h2(t,b) . Wo[cls] + bo ----------------
__global__ __launch_bounds__(320) void out_proj(const u16* __restrict__ H2,   // (S*B,512)
                                                const float* __restrict__ Wo, // (9,512)
                                                const float* __restrict__ bo,
                                                float* __restrict__ out) {    // (B,S,9)
  __shared__ __align__(16) u16 Hs[32 * 520];
  const int r0 = blockIdx.x * 32;     // flat row = t*256 + b
  const int tid = threadIdx.x;
  for (int e = tid; e < 2048; e += 320) {
    int rl = e >> 6, k8 = (e & 63) * 8;
    *(uint4*)&Hs[rl * 520 + k8] = *(const uint4*)(H2 + (size_t)(r0 + rl) * HID_ + k8);
  }
  __syncthreads();
  if (tid < 288) {
    int rl = tid / 9, cls = tid - rl * 9;
    const u16* h = &Hs[rl * 520];
    const float* wv = Wo + cls * HID_;
    float s = bo[cls];
#pragma unroll 8
    for (int k = 0; k < HID_; ++k) s += bf2f(h[k]) * wv[k];
    int r = r0 + rl, t = r >> 8, b = r & 255;
    out[((size_t)b * SEQ_ + t) * NCLS_ + cls] = s;
  }
}

extern "C" void kernel_launch(void* const* d_in, const int* in_sizes, int n_in,
                              void* d_out, int out_size, void* d_ws, size_t ws_size,
                              hipStream_t stream) {
  (void)in_sizes; (void)n_in; (void)out_size; (void)ws_size;
  const int*   ids = (const int*)d_in[0];
  const float* tok = (const float*)d_in[1];
  const float* pos = (const float*)d_in[2];
  const float* W1  = (const float*)d_in[3];
  const float* R1  = (const float*)d_in[4];
  const float* b1  = (const float*)d_in[5];
  const float* W2  = (const float*)d_in[6];
  const float* R2  = (const float*)d_in[7];
  const float* b2  = (const float*)d_in[8];
  const float* Wo  = (const float*)d_in[9];
  const float* bo  = (const float*)d_in[10];
  float* out = (float*)d_out;

  // workspace (~226 MB); H1all overlays Xbf (dead after phase A)
  char* p = (char*)d_ws;
  auto alloc = [&](size_t bytes) { char* q = p; p += (bytes + 255) & ~(size_t)255; return q; };
  u16*  W1b  = (u16*)alloc((size_t)NG_ * DIN_ * 2);                 // 3MB
  u16*  R1b  = (u16*)alloc((size_t)NG_ * HID_ * 2);                 // 2MB
  u16*  W2c  = (u16*)alloc((size_t)NG_ * 1024 * 2);                 // 4MB [W2|R2]
  int*  flags = (int*)alloc((size_t)2 * SEQ_ * 8 * 4);              // 8KB
  size_t xbf_bytes = (size_t)SEQ_ * BATCH_ * DIN_ * 2;              // 50.3MB
  u16*  Xbf  = (u16*)alloc(xbf_bytes);
  u16*  H1all = Xbf;                                                // overlay (32MB < 50.3MB)
  u16*  H2all = (u16*)alloc((size_t)SEQ_ * BATCH_ * HID_ * 2);      // 32MB
  u16*  Xpre = (u16*)alloc((size_t)SEQ_ * BATCH_ * NG_ * 2);        // 134MB
  int*  flags1 = flags;
  int*  flags2 = flags + SEQ_ * 8;

  // weight casts
  castk<<<dim3((NG_ * DIN_ / 4 + 255) / 256), 256, 0, stream>>>(W1, W1b, NG_ * DIN_ / 4);
  castk<<<dim3((NG_ * HID_ / 4 + 255) / 256), 256, 0, stream>>>(R1, R1b, NG_ * HID_ / 4);
  cast2<<<dim3(1024), 256, 0, stream>>>(W2, W2c, 0);
  cast2<<<dim3(1024), 256, 0, stream>>>(R2, W2c, 512);
  hipMemsetAsync(flags, 0, (size_t)2 * SEQ_ * 8 * 4, stream);

  // embeds -> (S,B,768) bf16
  embed_k<<<dim3(SEQ_ * BATCH_), 192, 0, stream>>>(ids, tok, pos, Xbf);

  // phase A: X1pre = X @ W1^T + b1   (32768 x 2048, K=768)
  gemm_bt<<<dim3(NG_ / 128, SEQ_ * BATCH_ / 128), 256, 0, stream>>>(
      Xbf, W1b, b1, Xpre, SEQ_ * BATCH_, NG_, DIN_);

  // layer-1 chain (persistent, flag-synced)
  {
    const u16* Hother = H1all;  // unused
    u16* Hself = H1all;
    const u16* Xp = Xpre;
    const float* b2a = b2;      // unused
    const u16* Bwa = R1b;
    int* fl = flags1;
    void* args[] = {(void*)&Hother, (void*)&Hself, (void*)&Xp,
                    (void*)&b2a, (void*)&Bwa, (void*)&fl};
    hipLaunchCooperativeKernel(reinterpret_cast<void*>(&lstm_chain<0>),
                               dim3(256), dim3(512), args, 0, stream);
  }
  // layer-2 chain
  {
    const u16* Hother = H1all;
    u16* Hself = H2all;
    const u16* Xp = Xpre;       // unused
    const float* b2a = b2;
    const u16* Bwa = W2c;
    int* fl = flags2;
    void* args[] = {(void*)&Hother, (void*)&Hself, (void*)&Xp,
                    (void*)&b2a, (void*)&Bwa, (void*)&fl};
    hipLaunchCooperativeKernel(reinterpret_cast<void*>(&lstm_chain<1>),
                               dim3(256), dim3(512), args, 0, stream);
  }

  // logits
  out_proj<<<dim3(SEQ_ * BATCH_ / 32), 320, 0, stream>>>(H2all, Wo, bo, out);
}